// Round 4
// baseline (714.545 us; speedup 1.0000x reference)
//
#include <hip/hip_runtime.h>

// Problem constants (B=8, Q=512, D=4096, H=1024)
#define BATCH 8
#define QLEN 512
#define DLEN 4096
#define HDIM 1024

// ---------- helpers ----------
typedef __attribute__((ext_vector_type(8))) short bf16x8;   // 8 bf16 in 4 VGPRs
typedef __attribute__((ext_vector_type(4))) float f32x4;
typedef __attribute__((ext_vector_type(4))) short s16x4;

__device__ __forceinline__ short f2bf(float f) {
    union { float f; unsigned u; } x; x.f = f;
    unsigned r = x.u + 0x7fffu + ((x.u >> 16) & 1u);   // RNE
    return (short)(r >> 16);
}

__device__ __forceinline__ void gload_lds16(const void* g, void* l) {
    __builtin_amdgcn_global_load_lds(
        (const __attribute__((address_space(1))) unsigned int*)g,
        (__attribute__((address_space(3))) unsigned int*)l,
        16, 0, 0);
}

#define WAIT_VMCNT(n) asm volatile("s_waitcnt vmcnt(" #n ")" ::: "memory")
#define WAIT_LGKM0    asm volatile("s_waitcnt lgkmcnt(0)" ::: "memory")

// ---------- prep kernels ----------
// fp32 -> bf16 elementwise (vectorized float4 -> short4)
__global__ void cvt_f32_bf16(const float* __restrict__ in, short* __restrict__ out, int n4) {
    int i = blockIdx.x * blockDim.x + threadIdx.x;
    int stride = gridDim.x * blockDim.x;
    for (; i < n4; i += stride) {
        float4 x = ((const float4*)in)[i];
        s16x4 o = { f2bf(x.x), f2bf(x.y), f2bf(x.z), f2bf(x.w) };
        ((s16x4*)out)[i] = o;
    }
}

// proj_w [h][k] f32 -> Wt [k][h] bf16  (1024x1024), 32x32 LDS tile transpose
__global__ void transpose_w(const float* __restrict__ W, short* __restrict__ Wt) {
    __shared__ float t[32][33];
    const int hb = blockIdx.y * 32, kb = blockIdx.x * 32;
    #pragma unroll
    for (int i = 0; i < 4; ++i) {
        int h = threadIdx.y + i * 8;
        t[h][threadIdx.x] = W[(size_t)(hb + h) * HDIM + kb + threadIdx.x];
    }
    __syncthreads();
    #pragma unroll
    for (int i = 0; i < 4; ++i) {
        int k = threadIdx.y + i * 8;
        Wt[(size_t)(kb + k) * HDIM + hb + threadIdx.x] = f2bf(t[threadIdx.x][k]);
    }
}

// docsB [b][d][h] bf16 -> docsT [b][h][d] bf16. 64x64 tile via uint LDS [64][65]
__global__ void transpose_docs(const short* __restrict__ docsB, short* __restrict__ docsT) {
    __shared__ unsigned t[64][65];
    const int b = blockIdx.z;
    const int h0 = blockIdx.x * 64, d0 = blockIdx.y * 64;
    const int tq = threadIdx.x & 15;
    const int tr = threadIdx.x >> 4;
    #pragma unroll
    for (int i = 0; i < 4; ++i) {
        int d = tr + i * 16;
        s16x4 v = *(const s16x4*)(docsB + ((size_t)b * DLEN + d0 + d) * HDIM + h0 + tq * 4);
        t[d][tq * 4 + 0] = (unsigned short)v[0];
        t[d][tq * 4 + 1] = (unsigned short)v[1];
        t[d][tq * 4 + 2] = (unsigned short)v[2];
        t[d][tq * 4 + 3] = (unsigned short)v[3];
    }
    __syncthreads();
    #pragma unroll
    for (int i = 0; i < 4; ++i) {
        int h = tr + i * 16;
        s16x4 o = { (short)t[tq * 4 + 0][h], (short)t[tq * 4 + 1][h],
                    (short)t[tq * 4 + 2][h], (short)t[tq * 4 + 3][h] };
        *(s16x4*)(docsT + ((size_t)b * HDIM + h0 + h) * DLEN + d0 + tq * 4) = o;
    }
}

// ---------- GEMM: D[i][j] = dot(A_i, B_j), A,B bf16 row-major in K ----------
// 128x128 tile, BK=64, DOUBLE-BUFFERED with counted vmcnt (T3+T4):
//   iter t: ds_read frags from buf[c] -> lgkmcnt(0)+barrier (read-done) ->
//   stage tile t+2 into buf[c] (just freed) -> MFMA (setprio) ->
//   vmcnt(8) [tile t+1 retired, t+2 stays IN FLIGHT across barrier] -> barrier.
// XOR chunk-swizzle (rule #21: linear LDS dest, pre-swizzled source, same XOR on read).
// T1 XCD chunk swizzle on 1D grid.
// EPI 0: bf16 out + bias   EPI 1: f32 out * scale   EPI 2: f32 out (partials)
#define BM 128
#define BN 128
#define BK 64
#define TILE_SH (BM * BK)   // shorts per A (or B) buffer

template<int EPI>
__global__ void gemm_bt(const short* __restrict__ A, const short* __restrict__ B,
                        void* __restrict__ Cv, const float* __restrict__ bias,
                        float scale, int N, int Kstride, int Kloop, int kOffStep,
                        int sx, int sxy,
                        long long aB, long long bB, long long cB) {
    __shared__ short As[2 * TILE_SH];
    __shared__ short Bs[2 * TILE_SH];
    const int tid  = threadIdx.x;
    const int lane = tid & 63;
    const int wv   = tid >> 6;
    const int wr   = wv >> 1, wc = wv & 1;

    // T1 XCD chunk swizzle (bijective since gridDim.x % 8 == 0)
    const int wg = (blockIdx.x & 7) * (gridDim.x >> 3) + (blockIdx.x >> 3);
    const int bx = wg & ((1 << sx) - 1);
    const int by = (wg >> sx) & ((1 << (sxy - sx)) - 1);
    const int z  = wg >> sxy;

    const size_t rowBase = (size_t)by * BM;
    const size_t colBase = (size_t)bx * BN;
    const int bb = z & 7;
    const int kOff = (z >> 3) * kOffStep;
    const short* Ag = A + (size_t)bb * aB + kOff;
    const short* Bg = B + (size_t)bb * bB + kOff;

    f32x4 acc[4][4];
    #pragma unroll
    for (int m = 0; m < 4; ++m)
        #pragma unroll
        for (int n = 0; n < 4; ++n)
            acc[m][n] = (f32x4){0.f, 0.f, 0.f, 0.f};

    // staging: 1024 chunks of 16B per tile, 4 per thread; precompute swizzled srcs
    const short* aSrc[4]; const short* bSrc[4]; int dOff[4];
    #pragma unroll
    for (int i = 0; i < 4; ++i) {
        const int c = tid + 256 * i;
        const int r = c >> 3, cc = c & 7;
        const int gk = (cc ^ (r & 7)) << 3;     // inverse-swizzled global chunk
        aSrc[i] = Ag + (rowBase + r) * (size_t)Kstride + gk;
        bSrc[i] = Bg + (colBase + r) * (size_t)Kstride + gk;
        dOff[i] = c * 8;                         // linear LDS dest offset (shorts)
    }
    const int lr = lane & 15;
    const int lk = (lane >> 4) << 3;            // 0,8,16,24 shorts

    const int nt = Kloop / BK;                  // always >= 2 here (K = 1024)

    // prologue: stage tile 0 -> buf0, tile 1 -> buf1; wait tile 0 only
    #pragma unroll
    for (int i = 0; i < 4; ++i) gload_lds16(aSrc[i], As + dOff[i]);
    #pragma unroll
    for (int i = 0; i < 4; ++i) gload_lds16(bSrc[i], Bs + dOff[i]);
    #pragma unroll
    for (int i = 0; i < 4; ++i) gload_lds16(aSrc[i] + BK, As + TILE_SH + dOff[i]);
    #pragma unroll
    for (int i = 0; i < 4; ++i) gload_lds16(bSrc[i] + BK, Bs + TILE_SH + dOff[i]);
    WAIT_VMCNT(8);
    __builtin_amdgcn_s_barrier();

    for (int t = 0; t < nt; ++t) {
        const int c = t & 1;
        const short* Ab = As + c * TILE_SH;
        const short* Bb = Bs + c * TILE_SH;

        // ds_read ALL frags for this K-tile into regs (XOR-swizzled)
        bf16x8 af[2][4], bfr[2][4];
        #pragma unroll
        for (int kk = 0; kk < 2; ++kk) {
            const int chunkL = (kk * 32 + lk) >> 3;
            #pragma unroll
            for (int m = 0; m < 4; ++m) {
                const int row = wr * 64 + m * 16 + lr;
                af[kk][m] = *(const bf16x8*)(Ab + row * BK + ((chunkL ^ (row & 7)) << 3));
            }
            #pragma unroll
            for (int n = 0; n < 4; ++n) {
                const int row = wc * 64 + n * 16 + lr;
                bfr[kk][n] = *(const bf16x8*)(Bb + row * BK + ((chunkL ^ (row & 7)) << 3));
            }
        }
        WAIT_LGKM0;                              // this wave's reads done
        __builtin_amdgcn_sched_barrier(0);       // rule #18 fence
        __builtin_amdgcn_s_barrier();            // ALL waves done reading buf[c]

        // stage tile t+2 into the just-freed buffer c (stays in flight past barrier-2)
        if (t + 2 < nt) {
            const int kt2 = (t + 2) * BK;
            #pragma unroll
            for (int i = 0; i < 4; ++i) gload_lds16(aSrc[i] + kt2, As + c * TILE_SH + dOff[i]);
            #pragma unroll
            for (int i = 0; i < 4; ++i) gload_lds16(bSrc[i] + kt2, Bs + c * TILE_SH + dOff[i]);
        }

        __builtin_amdgcn_s_setprio(1);
        #pragma unroll
        for (int kk = 0; kk < 2; ++kk)
            #pragma unroll
            for (int m = 0; m < 4; ++m)
                #pragma unroll
                for (int n = 0; n < 4; ++n)
                    acc[m][n] = __builtin_amdgcn_mfma_f32_16x16x32_bf16(af[kk][m], bfr[kk][n], acc[m][n], 0, 0, 0);
        __builtin_amdgcn_s_setprio(0);

        if (t + 1 < nt) {
            if (t + 2 < nt) { WAIT_VMCNT(8); }   // tile t+1 retired; t+2 still flying
            else           { WAIT_VMCNT(0); }    // last prefetch: drain
            __builtin_amdgcn_s_barrier();        // everyone's t+1 loads are in LDS
        }
    }

    // epilogue: C/D layout col=lane&15, row=(lane>>4)*4+reg  [m89/m91-verified]
    const int orow = (lane >> 4) << 2;
    const int ocol = lane & 15;
    #pragma unroll
    for (int n = 0; n < 4; ++n) {
        const size_t col = colBase + wc * 64 + n * 16 + ocol;
        const float bv = (EPI == 0) ? bias[col] : 0.f;
        #pragma unroll
        for (int m = 0; m < 4; ++m) {
            const size_t rbase = rowBase + wr * 64 + m * 16 + orow;
            #pragma unroll
            for (int j = 0; j < 4; ++j) {
                const float v = acc[m][n][j];
                const size_t off = (size_t)z * cB + (rbase + j) * (size_t)N + col;
                if (EPI == 0)      ((short*)Cv)[off] = f2bf(v + bv);
                else if (EPI == 1) ((float*)Cv)[off] = v * scale;
                else               ((float*)Cv)[off] = v;
            }
        }
    }
}

// ---------- split-K reduce: out4[i] = sum_{s<4} p4[i + s*2^20] ----------
__global__ void reduce4(const float* __restrict__ p, float* __restrict__ out, int n4) {
    int i = blockIdx.x * blockDim.x + threadIdx.x;
    const int stride = gridDim.x * blockDim.x;
    const float4* p4 = (const float4*)p;
    float4* o4 = (float4*)out;
    for (; i < n4; i += stride) {
        float4 a = p4[i];
        float4 b = p4[i + 1048576];
        float4 c = p4[i + 2097152];
        float4 d = p4[i + 3145728];
        float4 r;
        r.x = a.x + b.x + c.x + d.x;
        r.y = a.y + b.y + c.y + d.y;
        r.z = a.z + b.z + c.z + d.z;
        r.w = a.w + b.w + c.w + d.w;
        o4[i] = r;
    }
}

// ---------- masked row softmax over D=4096; writes f32 output + bf16 copy ----------
__global__ void softmax_rows(const float* __restrict__ scores, const int* __restrict__ mask,
                             float* __restrict__ attnF, short* __restrict__ attnB) {
    const int row = blockIdx.x;          // b*Q + q
    const int b   = row >> 9;            // / QLEN
    const int tid = threadIdx.x;
    const int lane = tid & 63;
    const int wv = tid >> 6;
    const float4* S  = (const float4*)(scores + (size_t)row * DLEN);
    const int4*   Mk = (const int4*)(mask + (size_t)b * DLEN);
    __shared__ float red[8];

    float v[16];
    float mx = -INFINITY;
    #pragma unroll
    for (int i = 0; i < 4; ++i) {
        float4 s = S[i * 256 + tid];
        int4   m = Mk[i * 256 + tid];
        v[i * 4 + 0] = m.x ? s.x : -INFINITY;
        v[i * 4 + 1] = m.y ? s.y : -INFINITY;
        v[i * 4 + 2] = m.z ? s.z : -INFINITY;
        v[i * 4 + 3] = m.w ? s.w : -INFINITY;
        #pragma unroll
        for (int c = 0; c < 4; ++c) mx = fmaxf(mx, v[i * 4 + c]);
    }
    #pragma unroll
    for (int o = 32; o > 0; o >>= 1) mx = fmaxf(mx, __shfl_xor(mx, o));
    if (lane == 0) red[wv] = mx;
    __syncthreads();
    mx = fmaxf(fmaxf(red[0], red[1]), fmaxf(red[2], red[3]));

    float sum = 0.f;
    #pragma unroll
    for (int i = 0; i < 16; ++i) {
        float e = __expf(v[i] - mx);   // masked: exp(-inf) = 0
        v[i] = e;
        sum += e;
    }
    #pragma unroll
    for (int o = 32; o > 0; o >>= 1) sum += __shfl_xor(sum, o);
    __syncthreads();
    if (lane == 0) red[4 + wv] = sum;
    __syncthreads();
    sum = red[4] + red[5] + red[6] + red[7];
    const float inv = 1.0f / sum;

    float4* OF = (float4*)(attnF + (size_t)row * DLEN);
    s16x4*  OB = (s16x4*)(attnB + (size_t)row * DLEN);
    #pragma unroll
    for (int i = 0; i < 4; ++i) {
        float4 w;
        w.x = v[i * 4 + 0] * inv;
        w.y = v[i * 4 + 1] * inv;
        w.z = v[i * 4 + 2] * inv;
        w.w = v[i * 4 + 3] * inv;
        OF[i * 256 + tid] = w;
        s16x4 o = { f2bf(w.x), f2bf(w.y), f2bf(w.z), f2bf(w.w) };
        OB[i * 256 + tid] = o;
    }
}

// ---------- launch ----------
extern "C" void kernel_launch(void* const* d_in, const int* in_sizes, int n_in,
                              void* d_out, int out_size, void* d_ws, size_t ws_size,
                              hipStream_t stream) {
    const float* qe   = (const float*)d_in[0];   // [8,512,1024]
    const float* docs = (const float*)d_in[1];   // [8,4096,1024]
    const int*   mask = (const int*)d_in[2];     // [8,4096]
    const float* pw   = (const float*)d_in[3];   // [1024,1024]
    const float* pb   = (const float*)d_in[4];   // [1024]

    float* outRet  = (float*)d_out;                          // [8,512,1024]
    float* outAttn = outRet + (size_t)BATCH * QLEN * HDIM;   // [8,512,4096]

    // workspace layout (bytes)
    char* ws = (char*)d_ws;
    short* qeB   = (short*)(ws + 0);            //  8 MiB: [4096][1024] bf16
    short* wt    = (short*)(ws + 8388608);      //  2 MiB: Wt [k][h] bf16
    short* qpB   = (short*)(ws + 10485760);     //  8 MiB: projected q bf16
    short* docsB = (short*)(ws + 18874368);     // 64 MiB: docs bf16 [b][d][h]
    short* docsT = (short*)(ws + 85983232);     // 64 MiB: docsT bf16 [b][h][d]
    float* scor  = (float*)(ws + 153092096);    // 64 MiB: scores f32 / GEMM3 partials
    short* attnB = (short*)(ws + 220200960);    // 32 MiB: attn bf16 [b][q][d]

    // prep: streaming cvt passes + bf16 transpose (reads L2/L3-hot docsB)
    cvt_f32_bf16<<<dim3(1024), dim3(256), 0, stream>>>(qe, qeB, (BATCH * QLEN * HDIM) / 4);
    cvt_f32_bf16<<<dim3(2048), dim3(256), 0, stream>>>(docs, docsB, (BATCH * DLEN * HDIM) / 4);
    transpose_w<<<dim3(32, 32), dim3(32, 8), 0, stream>>>(pw, wt);
    transpose_docs<<<dim3(HDIM / 64, DLEN / 64, BATCH), dim3(256), 0, stream>>>(docsB, docsT);

    // GEMM1: q = qe @ W + b   (M=4096, N=1024, K=1024) -> bf16
    // grid 256 = 8(x) * 32(y): sx=3, sxy=8 (z=0)
    gemm_bt<0><<<dim3(256), dim3(256), 0, stream>>>(
        qeB, wt, (void*)qpB, pb, 1.f, HDIM, HDIM, HDIM, 0, 3, 8,
        0LL, 0LL, 0LL);

    // GEMM2: scores = q @ docs^T * scale  (per batch M=512, N=4096, K=1024) -> f32
    // grid 1024 = 32(x) * 4(y) * 8(z): sx=5, sxy=7
    gemm_bt<1><<<dim3(1024), dim3(256), 0, stream>>>(
        qpB, docsB, (void*)scor, nullptr, 0.03125f, DLEN, HDIM, HDIM, 0, 5, 7,
        (long long)QLEN * HDIM, (long long)DLEN * HDIM, (long long)QLEN * DLEN);

    // softmax rows (4096 rows of 4096) -> f32 output + bf16 for PV
    softmax_rows<<<dim3(BATCH * QLEN), dim3(256), 0, stream>>>(scor, mask, outAttn, attnB);

    // GEMM3 split-K=4: partial[z=split*8+b] = attn @ docs over K-chunk of 1024
    // grid 1024 = 8(x) * 4(y) * 32(z): sx=3, sxy=5; partials overwrite scor
    gemm_bt<2><<<dim3(1024), dim3(256), 0, stream>>>(
        attnB, docsT, (void*)scor, nullptr, 1.f, HDIM, DLEN, DLEN / 4, DLEN / 4, 3, 5,
        (long long)QLEN * DLEN, (long long)HDIM * DLEN, (long long)QLEN * HDIM);

    // reduce partials -> retrieved docs
    reduce4<<<dim3(2048), dim3(256), 0, stream>>>(scor, outRet, (BATCH * QLEN * HDIM) / 4);
}

// Round 5
// 421.359 us; speedup vs baseline: 1.6958x; 1.6958x over previous
//
#include <hip/hip_runtime.h>

// Problem constants (B=8, Q=512, D=4096, H=1024)
#define BATCH 8
#define QLEN 512
#define DLEN 4096
#define HDIM 1024

// ---------- helpers ----------
typedef __attribute__((ext_vector_type(8))) short bf16x8;   // 8 bf16 in 4 VGPRs
typedef __attribute__((ext_vector_type(4))) float f32x4;
typedef __attribute__((ext_vector_type(4))) short s16x4;

__device__ __forceinline__ short f2bf(float f) {
    union { float f; unsigned u; } x; x.f = f;
    unsigned r = x.u + 0x7fffu + ((x.u >> 16) & 1u);   // RNE
    return (short)(r >> 16);
}

__device__ __forceinline__ void gload_lds16(const void* g, void* l) {
    __builtin_amdgcn_global_load_lds(
        (const __attribute__((address_space(1))) unsigned int*)g,
        (__attribute__((address_space(3))) unsigned int*)l,
        16, 0, 0);
}

// ---------- prep kernels ----------
// fp32 -> bf16 elementwise (vectorized float4 -> short4)
__global__ void cvt_f32_bf16(const float* __restrict__ in, short* __restrict__ out, int n4) {
    int i = blockIdx.x * blockDim.x + threadIdx.x;
    int stride = gridDim.x * blockDim.x;
    for (; i < n4; i += stride) {
        float4 x = ((const float4*)in)[i];
        s16x4 o = { f2bf(x.x), f2bf(x.y), f2bf(x.z), f2bf(x.w) };
        ((s16x4*)out)[i] = o;
    }
}

// proj_w [h][k] f32 -> Wt [k][h] bf16  (1024x1024), 32x32 LDS tile transpose
__global__ void transpose_w(const float* __restrict__ W, short* __restrict__ Wt) {
    __shared__ float t[32][33];
    const int hb = blockIdx.y * 32, kb = blockIdx.x * 32;
    #pragma unroll
    for (int i = 0; i < 4; ++i) {
        int h = threadIdx.y + i * 8;
        t[h][threadIdx.x] = W[(size_t)(hb + h) * HDIM + kb + threadIdx.x];
    }
    __syncthreads();
    #pragma unroll
    for (int i = 0; i < 4; ++i) {
        int k = threadIdx.y + i * 8;
        Wt[(size_t)(kb + k) * HDIM + hb + threadIdx.x] = f2bf(t[threadIdx.x][k]);
    }
}

// docsB [b][d][h] bf16 -> docsT [b][h][d] bf16. 64x64 tile via uint LDS [64][65]
__global__ void transpose_docs(const short* __restrict__ docsB, short* __restrict__ docsT) {
    __shared__ unsigned t[64][65];
    const int b = blockIdx.z;
    const int h0 = blockIdx.x * 64, d0 = blockIdx.y * 64;
    const int tq = threadIdx.x & 15;
    const int tr = threadIdx.x >> 4;
    #pragma unroll
    for (int i = 0; i < 4; ++i) {
        int d = tr + i * 16;
        s16x4 v = *(const s16x4*)(docsB + ((size_t)b * DLEN + d0 + d) * HDIM + h0 + tq * 4);
        t[d][tq * 4 + 0] = (unsigned short)v[0];
        t[d][tq * 4 + 1] = (unsigned short)v[1];
        t[d][tq * 4 + 2] = (unsigned short)v[2];
        t[d][tq * 4 + 3] = (unsigned short)v[3];
    }
    __syncthreads();
    #pragma unroll
    for (int i = 0; i < 4; ++i) {
        int h = tr + i * 16;
        s16x4 o = { (short)t[tq * 4 + 0][h], (short)t[tq * 4 + 1][h],
                    (short)t[tq * 4 + 2][h], (short)t[tq * 4 + 3][h] };
        *(s16x4*)(docsT + ((size_t)b * HDIM + h0 + h) * DLEN + d0 + tq * 4) = o;
    }
}

// ---------- GEMM: D[i][j] = dot(A_i, B_j), A,B bf16 row-major in K ----------
// 128x128 tile, BK=64, catalog "minimum 2-phase" double buffer (T3 recipe, m230-V0):
//   iter t: issue stage(t+1 -> buf c^1); ds_read+MFMA from buf c; __syncthreads.
//   __syncthreads drains vmcnt(0)+lgkmcnt(0) before s_barrier (compiler-emitted),
//   so RAW (next buf staged) and WAR (cur buf read before overwrite next iter) hold.
// NO inline asm, NO setprio (T5 null on 2-phase, m190). Only 8 frags live per kk
// phase (round 4's 16-live-frags + asm barriers caused VGPR spill, WRITE_SIZE 4x).
// XOR chunk-swizzle (rule #21: linear LDS dest, pre-swizzled source, same XOR on read).
// T1 XCD chunk swizzle on 1D grid.
// EPI 0: bf16 out + bias   EPI 1: f32 out * scale   EPI 2: f32 out (partials)
#define BM 128
#define BN 128
#define BK 64
#define TILE_SH (BM * BK)   // shorts per A (or B) buffer

template<int EPI>
__global__ void gemm_bt(const short* __restrict__ A, const short* __restrict__ B,
                        void* __restrict__ Cv, const float* __restrict__ bias,
                        float scale, int N, int Kstride, int Kloop, int kOffStep,
                        int sx, int sxy,
                        long long aB, long long bB, long long cB) {
    __shared__ short As[2 * TILE_SH];
    __shared__ short Bs[2 * TILE_SH];
    const int tid  = threadIdx.x;
    const int lane = tid & 63;
    const int wv   = tid >> 6;
    const int wr   = wv >> 1, wc = wv & 1;

    // T1 XCD chunk swizzle (bijective since gridDim.x % 8 == 0)
    const int wg = (blockIdx.x & 7) * (gridDim.x >> 3) + (blockIdx.x >> 3);
    const int bx = wg & ((1 << sx) - 1);
    const int by = (wg >> sx) & ((1 << (sxy - sx)) - 1);
    const int z  = wg >> sxy;

    const size_t rowBase = (size_t)by * BM;
    const size_t colBase = (size_t)bx * BN;
    const int bb = z & 7;
    const int kOff = (z >> 3) * kOffStep;
    const short* Ag = A + (size_t)bb * aB + kOff;
    const short* Bg = B + (size_t)bb * bB + kOff;

    f32x4 acc[4][4];
    #pragma unroll
    for (int m = 0; m < 4; ++m)
        #pragma unroll
        for (int n = 0; n < 4; ++n)
            acc[m][n] = (f32x4){0.f, 0.f, 0.f, 0.f};

    // staging: 1024 chunks of 16B per tile, 4 per thread; precompute swizzled srcs
    const short* aSrc[4]; const short* bSrc[4]; int dOff[4];
    #pragma unroll
    for (int i = 0; i < 4; ++i) {
        const int c = tid + 256 * i;
        const int r = c >> 3, cc = c & 7;
        const int gk = (cc ^ (r & 7)) << 3;     // inverse-swizzled global chunk
        aSrc[i] = Ag + (rowBase + r) * (size_t)Kstride + gk;
        bSrc[i] = Bg + (colBase + r) * (size_t)Kstride + gk;
        dOff[i] = c * 8;                         // linear LDS dest offset (shorts)
    }
    const int lr = lane & 15;
    const int lk = (lane >> 4) << 3;            // 0,8,16,24 shorts

    const int nt = Kloop / BK;                  // >= 2 for all our shapes

    // prologue: stage tile 0 -> buf0; full drain via __syncthreads
    #pragma unroll
    for (int i = 0; i < 4; ++i) gload_lds16(aSrc[i], As + dOff[i]);
    #pragma unroll
    for (int i = 0; i < 4; ++i) gload_lds16(bSrc[i], Bs + dOff[i]);
    __syncthreads();

    int cur = 0;
    for (int t = 0; t < nt; ++t) {
        // issue next tile's loads into the other buffer; they fly under the MFMAs
        if (t + 1 < nt) {
            const int kt = (t + 1) * BK;
            const int o = (cur ^ 1) * TILE_SH;
            #pragma unroll
            for (int i = 0; i < 4; ++i) gload_lds16(aSrc[i] + kt, As + o + dOff[i]);
            #pragma unroll
            for (int i = 0; i < 4; ++i) gload_lds16(bSrc[i] + kt, Bs + o + dOff[i]);
        }

        const short* Ab = As + cur * TILE_SH;
        const short* Bb = Bs + cur * TILE_SH;
        #pragma unroll
        for (int kk = 0; kk < 2; ++kk) {
            const int chunkL = (kk * 32 + lk) >> 3;   // logical chunk 0..7
            bf16x8 af[4], bfr[4];
            #pragma unroll
            for (int m = 0; m < 4; ++m) {
                const int row = wr * 64 + m * 16 + lr;
                af[m] = *(const bf16x8*)(Ab + row * BK + ((chunkL ^ (row & 7)) << 3));
            }
            #pragma unroll
            for (int n = 0; n < 4; ++n) {
                const int row = wc * 64 + n * 16 + lr;
                bfr[n] = *(const bf16x8*)(Bb + row * BK + ((chunkL ^ (row & 7)) << 3));
            }
            #pragma unroll
            for (int m = 0; m < 4; ++m)
                #pragma unroll
                for (int n = 0; n < 4; ++n)
                    acc[m][n] = __builtin_amdgcn_mfma_f32_16x16x32_bf16(af[m], bfr[n], acc[m][n], 0, 0, 0);
        }
        __syncthreads();   // drains vmcnt(0): next buf staged; all waves done reading cur
        cur ^= 1;
    }

    // epilogue: C/D layout col=lane&15, row=(lane>>4)*4+reg  [m89/m91-verified]
    const int orow = (lane >> 4) << 2;
    const int ocol = lane & 15;
    #pragma unroll
    for (int n = 0; n < 4; ++n) {
        const size_t col = colBase + wc * 64 + n * 16 + ocol;
        const float bv = (EPI == 0) ? bias[col] : 0.f;
        #pragma unroll
        for (int m = 0; m < 4; ++m) {
            const size_t rbase = rowBase + wr * 64 + m * 16 + orow;
            #pragma unroll
            for (int j = 0; j < 4; ++j) {
                const float v = acc[m][n][j];
                const size_t off = (size_t)z * cB + (rbase + j) * (size_t)N + col;
                if (EPI == 0)      ((short*)Cv)[off] = f2bf(v + bv);
                else if (EPI == 1) ((float*)Cv)[off] = v * scale;
                else               ((float*)Cv)[off] = v;
            }
        }
    }
}

// ---------- split-K reduce: out4[i] = sum_{s<4} p4[i + s*2^20] ----------
__global__ void reduce4(const float* __restrict__ p, float* __restrict__ out, int n4) {
    int i = blockIdx.x * blockDim.x + threadIdx.x;
    const int stride = gridDim.x * blockDim.x;
    const float4* p4 = (const float4*)p;
    float4* o4 = (float4*)out;
    for (; i < n4; i += stride) {
        float4 a = p4[i];
        float4 b = p4[i + 1048576];
        float4 c = p4[i + 2097152];
        float4 d = p4[i + 3145728];
        float4 r;
        r.x = a.x + b.x + c.x + d.x;
        r.y = a.y + b.y + c.y + d.y;
        r.z = a.z + b.z + c.z + d.z;
        r.w = a.w + b.w + c.w + d.w;
        o4[i] = r;
    }
}

// ---------- masked row softmax over D=4096; writes f32 output + bf16 copy ----------
__global__ void softmax_rows(const float* __restrict__ scores, const int* __restrict__ mask,
                             float* __restrict__ attnF, short* __restrict__ attnB) {
    const int row = blockIdx.x;          // b*Q + q
    const int b   = row >> 9;            // / QLEN
    const int tid = threadIdx.x;
    const int lane = tid & 63;
    const int wv = tid >> 6;
    const float4* S  = (const float4*)(scores + (size_t)row * DLEN);
    const int4*   Mk = (const int4*)(mask + (size_t)b * DLEN);
    __shared__ float red[8];

    float v[16];
    float mx = -INFINITY;
    #pragma unroll
    for (int i = 0; i < 4; ++i) {
        float4 s = S[i * 256 + tid];
        int4   m = Mk[i * 256 + tid];
        v[i * 4 + 0] = m.x ? s.x : -INFINITY;
        v[i * 4 + 1] = m.y ? s.y : -INFINITY;
        v[i * 4 + 2] = m.z ? s.z : -INFINITY;
        v[i * 4 + 3] = m.w ? s.w : -INFINITY;
        #pragma unroll
        for (int c = 0; c < 4; ++c) mx = fmaxf(mx, v[i * 4 + c]);
    }
    #pragma unroll
    for (int o = 32; o > 0; o >>= 1) mx = fmaxf(mx, __shfl_xor(mx, o));
    if (lane == 0) red[wv] = mx;
    __syncthreads();
    mx = fmaxf(fmaxf(red[0], red[1]), fmaxf(red[2], red[3]));

    float sum = 0.f;
    #pragma unroll
    for (int i = 0; i < 16; ++i) {
        float e = __expf(v[i] - mx);   // masked: exp(-inf) = 0
        v[i] = e;
        sum += e;
    }
    #pragma unroll
    for (int o = 32; o > 0; o >>= 1) sum += __shfl_xor(sum, o);
    __syncthreads();
    if (lane == 0) red[4 + wv] = sum;
    __syncthreads();
    sum = red[4] + red[5] + red[6] + red[7];
    const float inv = 1.0f / sum;

    float4* OF = (float4*)(attnF + (size_t)row * DLEN);
    s16x4*  OB = (s16x4*)(attnB + (size_t)row * DLEN);
    #pragma unroll
    for (int i = 0; i < 4; ++i) {
        float4 w;
        w.x = v[i * 4 + 0] * inv;
        w.y = v[i * 4 + 1] * inv;
        w.z = v[i * 4 + 2] * inv;
        w.w = v[i * 4 + 3] * inv;
        OF[i * 256 + tid] = w;
        s16x4 o = { f2bf(w.x), f2bf(w.y), f2bf(w.z), f2bf(w.w) };
        OB[i * 256 + tid] = o;
    }
}

// ---------- launch ----------
extern "C" void kernel_launch(void* const* d_in, const int* in_sizes, int n_in,
                              void* d_out, int out_size, void* d_ws, size_t ws_size,
                              hipStream_t stream) {
    const float* qe   = (const float*)d_in[0];   // [8,512,1024]
    const float* docs = (const float*)d_in[1];   // [8,4096,1024]
    const int*   mask = (const int*)d_in[2];     // [8,4096]
    const float* pw   = (const float*)d_in[3];   // [1024,1024]
    const float* pb   = (const float*)d_in[4];   // [1024]

    float* outRet  = (float*)d_out;                          // [8,512,1024]
    float* outAttn = outRet + (size_t)BATCH * QLEN * HDIM;   // [8,512,4096]

    // workspace layout (bytes)
    char* ws = (char*)d_ws;
    short* qeB   = (short*)(ws + 0);            //  8 MiB: [4096][1024] bf16
    short* wt    = (short*)(ws + 8388608);      //  2 MiB: Wt [k][h] bf16
    short* qpB   = (short*)(ws + 10485760);     //  8 MiB: projected q bf16
    short* docsB = (short*)(ws + 18874368);     // 64 MiB: docs bf16 [b][d][h]
    short* docsT = (short*)(ws + 85983232);     // 64 MiB: docsT bf16 [b][h][d]
    float* scor  = (float*)(ws + 153092096);    // 64 MiB: scores f32 / GEMM3 partials
    short* attnB = (short*)(ws + 220200960);    // 32 MiB: attn bf16 [b][q][d]

    // prep: streaming cvt passes + bf16 transpose (reads L2/L3-hot docsB)
    cvt_f32_bf16<<<dim3(1024), dim3(256), 0, stream>>>(qe, qeB, (BATCH * QLEN * HDIM) / 4);
    cvt_f32_bf16<<<dim3(2048), dim3(256), 0, stream>>>(docs, docsB, (BATCH * DLEN * HDIM) / 4);
    transpose_w<<<dim3(32, 32), dim3(32, 8), 0, stream>>>(pw, wt);
    transpose_docs<<<dim3(HDIM / 64, DLEN / 64, BATCH), dim3(256), 0, stream>>>(docsB, docsT);

    // GEMM1: q = qe @ W + b   (M=4096, N=1024, K=1024) -> bf16
    // grid 256 = 8(x) * 32(y): sx=3, sxy=8 (z=0)
    gemm_bt<0><<<dim3(256), dim3(256), 0, stream>>>(
        qeB, wt, (void*)qpB, pb, 1.f, HDIM, HDIM, HDIM, 0, 3, 8,
        0LL, 0LL, 0LL);

    // GEMM2: scores = q @ docs^T * scale  (per batch M=512, N=4096, K=1024) -> f32
    // grid 1024 = 32(x) * 4(y) * 8(z): sx=5, sxy=7
    gemm_bt<1><<<dim3(1024), dim3(256), 0, stream>>>(
        qpB, docsB, (void*)scor, nullptr, 0.03125f, DLEN, HDIM, HDIM, 0, 5, 7,
        (long long)QLEN * HDIM, (long long)DLEN * HDIM, (long long)QLEN * DLEN);

    // softmax rows (4096 rows of 4096) -> f32 output + bf16 for PV
    softmax_rows<<<dim3(BATCH * QLEN), dim3(256), 0, stream>>>(scor, mask, outAttn, attnB);

    // GEMM3 split-K=4: partial[z=split*8+b] = attn @ docs over K-chunk of 1024
    // grid 1024 = 8(x) * 4(y) * 32(z): sx=3, sxy=5; partials overwrite scor
    gemm_bt<2><<<dim3(1024), dim3(256), 0, stream>>>(
        attnB, docsT, (void*)scor, nullptr, 1.f, HDIM, DLEN, DLEN / 4, DLEN / 4, 3, 5,
        (long long)QLEN * DLEN, (long long)HDIM * DLEN, (long long)QLEN * HDIM);

    // reduce partials -> retrieved docs
    reduce4<<<dim3(2048), dim3(256), 0, stream>>>(scor, outRet, (BATCH * QLEN * HDIM) / 4);
}